// Round 2
// baseline (4429.749 us; speedup 1.0000x reference)
//
#include <hip/hip_runtime.h>
#include <hip/hip_cooperative_groups.h>

namespace cg = cooperative_groups;

// Problem constants
#define B_ 256
#define T_ 64
#define V_ 10000
#define E_ 512
#define H_ 1024
#define G_ 4096   // 4*H

typedef __attribute__((ext_vector_type(8))) short short8;
typedef __attribute__((ext_vector_type(4))) float f32x4;

static __device__ __forceinline__ float bf2f(unsigned short u) {
    return __uint_as_float(((unsigned int)u) << 16);
}
static __device__ __forceinline__ unsigned short f2bf(float f) {
    unsigned int i = __float_as_uint(f);
    unsigned int r = (i + 0x7FFFu + ((i >> 16) & 1u)) >> 16;
    return (unsigned short)r;
}
static __device__ __forceinline__ float sigmoid_f(float x) {
    return 1.0f / (1.0f + __expf(-x));
}
static __device__ __forceinline__ float tanh_f(float x) {
    return 1.0f - 2.0f / (__expf(2.0f * x) + 1.0f);
}

// async global->LDS, 16B per lane; LDS dest = wave-uniform base + lane*16
static __device__ __forceinline__ void gload16(const void* g, void* l) {
    __builtin_amdgcn_global_load_lds((const __attribute__((address_space(1))) void*)g,
                                     (__attribute__((address_space(3))) void*)l, 16, 0, 0);
}

// ---------------------------------------------------------------------------
// fp32 -> bf16 convert
__global__ __launch_bounds__(256) void k_cvt(const float* __restrict__ in,
                                             unsigned short* __restrict__ out, int n4) {
    int i = blockIdx.x * 256 + threadIdx.x;
    if (i >= n4) return;
    float4 v = reinterpret_cast<const float4*>(in)[i];
    uint2 p;
    p.x = (unsigned int)f2bf(v.x) | ((unsigned int)f2bf(v.y) << 16);
    p.y = (unsigned int)f2bf(v.z) | ((unsigned int)f2bf(v.w) << 16);
    reinterpret_cast<uint2*>(out)[i] = p;
}

// ---------------------------------------------------------------------------
// W[K][N] fp32 -> WT[N][K] bf16
__global__ __launch_bounds__(256) void k_transpose(const float* __restrict__ w,
                                                   unsigned short* __restrict__ wT,
                                                   int K, int N) {
    __shared__ float tile[32][33];
    int nblk = N >> 5;
    int bx = blockIdx.x % nblk;
    int by = blockIdx.x / nblk;
    int lx = threadIdx.x & 31;
    int ly = threadIdx.x >> 5;
    int k0 = by * 32, n0 = bx * 32;
#pragma unroll
    for (int i = 0; i < 32; i += 8)
        tile[ly + i][lx] = w[(size_t)(k0 + ly + i) * N + n0 + lx];
    __syncthreads();
#pragma unroll
    for (int i = 0; i < 32; i += 8)
        wT[(size_t)(n0 + ly + i) * K + k0 + lx] = f2bf(tile[lx][ly + i]);
}

// ---------------------------------------------------------------------------
// xg[B*T][G] = bf16( embed[seq] @ x2h_w + x2h_b )   (bias added here)
// m97-style: 128x128 tile, BK=32, 4 waves (2x2), wave = 64x64 = acc[4][4],
// global_load_lds width-16 staging (per-lane gathered source rows for A).
__global__ __launch_bounds__(256) void k_xg(const int* __restrict__ seq,
                                            const unsigned short* __restrict__ emb,  // [V][E]
                                            const unsigned short* __restrict__ wT,   // [G][E]
                                            const float* __restrict__ bias,          // [G]
                                            unsigned short* __restrict__ xg) {       // [B*T][G]
    const int mt = blockIdx.x & 127;  // 128 M-tiles
    const int nt = blockIdx.x >> 7;   // 32 N-tiles
    const int tid = threadIdx.x;
    const int w = tid >> 6, l = tid & 63, g = l >> 4, li = l & 15;
    const int wr = w >> 1, wc = w & 1;

    __shared__ unsigned short As[128 * 32];  // 8 KB, linear row-major [row][k]
    __shared__ unsigned short Bs[128 * 32];  // 8 KB
    __shared__ int seqv[128];

    if (tid < 128) seqv[tid] = seq[mt * 128 + tid];
    __syncthreads();

    // staging: wave w, issue j covers tile rows j*64 + w*16 + (l>>2), k-granule l&3
    const int r0 = w * 16 + (l >> 2);
    const int kc = (l & 3) * 8;
    const unsigned short* asrc0 = emb + (size_t)seqv[r0] * E_ + kc;
    const unsigned short* asrc1 = emb + (size_t)seqv[r0 + 64] * E_ + kc;
    const unsigned short* bsrc0 = wT + (size_t)(nt * 128 + r0) * E_ + kc;
    const unsigned short* bsrc1 = wT + (size_t)(nt * 128 + r0 + 64) * E_ + kc;
    char* aldsw = (char*)As + w * 1024;  // wave-uniform
    char* bldsw = (char*)Bs + w * 1024;

    f32x4 acc[4][4] = {};
    for (int k0 = 0; k0 < E_; k0 += 32) {
        gload16(asrc0 + k0, aldsw);
        gload16(asrc1 + k0, aldsw + 4096);
        gload16(bsrc0 + k0, bldsw);
        gload16(bsrc1 + k0, bldsw + 4096);
        __syncthreads();  // drains vmcnt(0) -> LDS ready
        short8 af[4], bf[4];
#pragma unroll
        for (int i = 0; i < 4; ++i) {
            af[i] = *(const short8*)(As + (wr * 64 + i * 16 + li) * 32 + g * 8);
            bf[i] = *(const short8*)(Bs + (wc * 64 + i * 16 + li) * 32 + g * 8);
        }
#pragma unroll
        for (int i = 0; i < 4; ++i)
#pragma unroll
            for (int j = 0; j < 4; ++j)
                acc[i][j] = __builtin_amdgcn_mfma_f32_16x16x32_bf16(af[i], bf[j], acc[i][j], 0, 0, 0);
        __syncthreads();
    }

#pragma unroll
    for (int j = 0; j < 4; ++j) {
        const int col = nt * 128 + wc * 64 + j * 16 + li;
        const float bv = bias[col];
#pragma unroll
        for (int i = 0; i < 4; ++i) {
            const int row = mt * 128 + wr * 64 + i * 16 + g * 4;
#pragma unroll
            for (int r = 0; r < 4; ++r)
                xg[(size_t)(row + r) * G_ + col] = f2bf(acc[i][j][r] + bv);
        }
    }
}

// ---------------------------------------------------------------------------
// Persistent LSTM recurrence. Cooperative launch: 256 WGs x 256 threads,
// 1 WG/CU. WG (rb,cb): batch rows rb*64..+63, h-cols cb*16..+15 (all 4 gates).
// h2h^T slice (64 rows x 1024 k, bf16 = 128 KB) lives in LDS for all 64 steps,
// XOR-swizzled (granule ^ (row&7)) so stride-2048B ds_read_b128 is conflict-free.
// c and the lane's own h stay in registers; h ping-pongs in global bf16.
__global__ __launch_bounds__(256) void k_rnn(const unsigned short* __restrict__ xg,  // [B][T][G]
                                             const unsigned short* __restrict__ wT,  // [G][H]
                                             const float* __restrict__ bias,         // [G]
                                             const int* __restrict__ seq_len,        // [B]
                                             unsigned short* __restrict__ h0,        // [B][H]
                                             unsigned short* __restrict__ h1,        // [B][H]
                                             float* __restrict__ hs,                 // [B][T][H]
                                             float* __restrict__ cs) {               // [B][T][H]
    const int wg = blockIdx.x;
    const int rb = wg & 3, cb = wg >> 2;
    const int tid = threadIdx.x;
    const int w = tid >> 6, l = tid & 63, g = l >> 4, li = l & 15;

    __shared__ unsigned short Bs[64 * 1024];  // 128 KB

    // stage B once: 8192 granules of 16 B; row n -> wT row (n>>4)*1024 + cb*16 + (n&15)
    for (int gi = 0; gi < 32; ++gi) {
        int gidx = gi * 256 + tid;
        int row = gidx >> 7, gr = gidx & 127;
        int grow = (row >> 4) * 1024 + cb * 16 + (row & 15);
        int4 v = *(const int4*)(wT + (size_t)grow * H_ + gr * 8);
        int dst = row * 128 + (gr ^ (row & 7));
        *(int4*)((char*)Bs + (size_t)dst * 16) = v;
    }

    const int hc = cb * 16 + li;
    float bv[4];
#pragma unroll
    for (int q = 0; q < 4; ++q) bv[q] = bias[q * 1024 + hc];
    const int m0 = rb * 64 + w * 16 + g * 4;
    int sl[4];
#pragma unroll
    for (int r = 0; r < 4; ++r) sl[r] = seq_len[m0 + r];
    float creg[4] = {0.f, 0.f, 0.f, 0.f};
    float hreg[4] = {0.f, 0.f, 0.f, 0.f};

    const int arow_i = rb * 64 + w * 16 + li;   // the A-row this lane reads
    const int lx7 = li & 7;
    const char* bbase = (const char*)Bs + li * 2048;

    __syncthreads();  // Bs ready (block-local); h0 zeroed by memsetAsync pre-launch

    cg::grid_group grid = cg::this_grid();

    for (int t = 0; t < T_; ++t) {
        const unsigned short* h_in = (t & 1) ? h1 : h0;
        unsigned short* h_out = (t & 1) ? h0 : h1;
        const unsigned short* arow = h_in + (size_t)arow_i * H_ + g * 8;

        f32x4 acc[4] = {};
        short8 pf[8];
#pragma unroll
        for (int p = 0; p < 8; ++p) pf[p] = *(const short8*)(arow + p * 32);
#pragma unroll
        for (int kk = 0; kk < 32; ++kk) {
            short8 af = pf[kk & 7];
            if (kk < 24) pf[kk & 7] = *(const short8*)(arow + (kk + 8) * 32);
            const int off = ((kk * 4 + g) ^ lx7) << 4;
#pragma unroll
            for (int q = 0; q < 4; ++q) {
                short8 bf = *(const short8*)(bbase + q * 32768 + off);
                acc[q] = __builtin_amdgcn_mfma_f32_16x16x32_bf16(af, bf, acc[q], 0, 0, 0);
            }
        }

        // pointwise + masked update; lane owns rows m0..m0+3 x col hc
#pragma unroll
        for (int r = 0; r < 4; ++r) {
            const int m = m0 + r;
            const size_t xoff = ((size_t)m * T_ + t) * G_ + hc;
            float xi = bf2f(xg[xoff]);
            float xf = bf2f(xg[xoff + 1024]);
            float xgv = bf2f(xg[xoff + 2048]);
            float xo = bf2f(xg[xoff + 3072]);
            float ig = sigmoid_f(acc[0][r] + bv[0] + xi);
            float fg = sigmoid_f(acc[1][r] + bv[1] + xf);
            float gg = tanh_f(acc[2][r] + bv[2] + xgv);
            float og = sigmoid_f(acc[3][r] + bv[3] + xo);
            float cn = fg * creg[r] + ig * gg;
            float hn = og * tanh_f(cn);
            bool valid = t < sl[r];
            if (valid) { creg[r] = cn; hreg[r] = hn; }
            const size_t ooff = ((size_t)m * T_ + t) * H_ + hc;
            hs[ooff] = valid ? hn : 0.0f;
            cs[ooff] = valid ? cn : 0.0f;
            h_out[(size_t)m * H_ + hc] = f2bf(hreg[r]);
        }
        __threadfence();
        grid.sync();
    }
}

// ---------------------------------------------------------------------------
// final_hidden[B][H] = tanh(h_last @ aff_w + aff_b)
__global__ __launch_bounds__(256) void k_final(const unsigned short* __restrict__ h,
                                               const unsigned short* __restrict__ wT,
                                               const float* __restrict__ bias,
                                               float* __restrict__ fin) {
    const int rb = blockIdx.x & 3;
    const int nb = blockIdx.x >> 2;
    const int tid = threadIdx.x;
    const int w = tid >> 6;
    const int l = tid & 63;
    const int g = l >> 4, li = l & 15;

    __shared__ unsigned short As[64][40];
    __shared__ unsigned short Bs[64][40];

    const int srow = tid >> 2;
    const int scol = (tid & 3) * 8;
    const unsigned short* aptr = h + (size_t)(rb * 64 + srow) * H_ + scol;
    const unsigned short* bptr = wT + (size_t)(nb * 64 + srow) * H_ + scol;

    f32x4 acc[4] = {};
    int4 ra = *(const int4*)aptr;
    int4 rb2 = *(const int4*)bptr;
    for (int kk = 0; kk < H_; kk += 32) {
        *(int4*)&As[srow][scol] = ra;
        *(int4*)&Bs[srow][scol] = rb2;
        __syncthreads();
        if (kk + 32 < H_) {
            ra = *(const int4*)(aptr + kk + 32);
            rb2 = *(const int4*)(bptr + kk + 32);
        }
        short8 af = *(const short8*)&As[w * 16 + li][g * 8];
#pragma unroll
        for (int q = 0; q < 4; ++q) {
            short8 bf = *(const short8*)&Bs[q * 16 + li][g * 8];
            acc[q] = __builtin_amdgcn_mfma_f32_16x16x32_bf16(af, bf, acc[q], 0, 0, 0);
        }
        __syncthreads();
    }
    const int m0 = rb * 64 + w * 16 + g * 4;
#pragma unroll
    for (int q = 0; q < 4; ++q) {
        int col = nb * 64 + q * 16 + li;
        float bv = bias[col];
#pragma unroll
        for (int r = 0; r < 4; ++r)
            fin[(size_t)(m0 + r) * H_ + col] = tanh_f(acc[q][r] + bv);
    }
}

// ---------------------------------------------------------------------------
__global__ __launch_bounds__(256) void k_mask(const int* __restrict__ seq_len,
                                              float* __restrict__ mask) {
    int i = blockIdx.x * 256 + threadIdx.x;
    int b = i >> 6, t = i & 63;
    mask[i] = (t < seq_len[b]) ? 1.0f : 0.0f;
}

// ---------------------------------------------------------------------------
extern "C" void kernel_launch(void* const* d_in, const int* in_sizes, int n_in,
                              void* d_out, int out_size, void* d_ws, size_t ws_size,
                              hipStream_t stream) {
    const int* seq = (const int*)d_in[0];
    const int* seq_len = (const int*)d_in[1];
    const float* embed = (const float*)d_in[2];
    const float* x2h_w = (const float*)d_in[3];
    const float* x2h_b = (const float*)d_in[4];
    const float* h2h_w = (const float*)d_in[5];
    const float* h2h_b = (const float*)d_in[6];
    const float* aff_w = (const float*)d_in[7];
    const float* aff_b = (const float*)d_in[8];

    float* out = (float*)d_out;
    float* hs = out;
    float* cs = out + (size_t)B_ * T_ * H_;
    float* fin = cs + (size_t)B_ * T_ * H_;
    float* mask = fin + (size_t)B_ * H_;

    char* p = (char*)d_ws;
    unsigned short* emb_b = (unsigned short*)p; p += (size_t)V_ * E_ * 2;
    unsigned short* x2h_t = (unsigned short*)p; p += (size_t)G_ * E_ * 2;
    unsigned short* h2h_t = (unsigned short*)p; p += (size_t)G_ * H_ * 2;
    unsigned short* aff_t = (unsigned short*)p; p += (size_t)H_ * H_ * 2;
    unsigned short* xg    = (unsigned short*)p; p += (size_t)B_ * T_ * G_ * 2;
    unsigned short* hbuf0 = (unsigned short*)p; p += (size_t)B_ * H_ * 2;
    unsigned short* hbuf1 = (unsigned short*)p; p += (size_t)B_ * H_ * 2;

    // 1) precompute bf16 operands
    hipLaunchKernelGGL(k_cvt, dim3((V_ * E_ / 4 + 255) / 256), dim3(256), 0, stream,
                       embed, emb_b, V_ * E_ / 4);
    hipLaunchKernelGGL(k_transpose, dim3((E_ / 32) * (G_ / 32)), dim3(256), 0, stream,
                       x2h_w, x2h_t, E_, G_);
    hipLaunchKernelGGL(k_transpose, dim3((H_ / 32) * (G_ / 32)), dim3(256), 0, stream,
                       h2h_w, h2h_t, H_, G_);
    hipLaunchKernelGGL(k_transpose, dim3((H_ / 32) * (H_ / 32)), dim3(256), 0, stream,
                       aff_w, aff_t, H_, H_);

    // 2) xg = embed[seq] @ x2h_w + b
    hipLaunchKernelGGL(k_xg, dim3(128 * 32), dim3(256), 0, stream,
                       seq, emb_b, x2h_t, x2h_b, xg);

    // 3) zero initial h (ping buffer)
    hipMemsetAsync(hbuf0, 0, (size_t)B_ * H_ * 2, stream);

    // 4) persistent cooperative recurrence (one grid sync per step)
    {
        const unsigned short* xg_p = xg;
        const unsigned short* wT_p = h2h_t;
        const float* b_p = h2h_b;
        const int* sl_p = seq_len;
        unsigned short* h0_p = hbuf0;
        unsigned short* h1_p = hbuf1;
        float* hs_p = hs;
        float* cs_p = cs;
        void* args[] = {(void*)&xg_p, (void*)&wT_p, (void*)&b_p, (void*)&sl_p,
                        (void*)&h0_p, (void*)&h1_p, (void*)&hs_p, (void*)&cs_p};
        hipLaunchCooperativeKernel(reinterpret_cast<void*>(k_rnn), dim3(256), dim3(256),
                                   args, 0, stream);
    }

    // 5) final affine (h after t=63 lives in hbuf0) + mask
    hipLaunchKernelGGL(k_final, dim3(64), dim3(256), 0, stream, hbuf0, aff_t, aff_b, fin);
    hipLaunchKernelGGL(k_mask, dim3(B_ * T_ / 256), dim3(256), 0, stream, seq_len, mask);
}

// Round 3
// 3135.831 us; speedup vs baseline: 1.4126x; 1.4126x over previous
//
#include <hip/hip_runtime.h>
#include <hip/hip_cooperative_groups.h>

// Problem constants
#define B_ 256
#define T_ 64
#define V_ 10000
#define E_ 512
#define H_ 1024
#define G_ 4096   // 4*H
#define NWG_ 256

typedef __attribute__((ext_vector_type(8))) short short8;
typedef __attribute__((ext_vector_type(4))) float f32x4;

static __device__ __forceinline__ float bf2f(unsigned short u) {
    return __uint_as_float(((unsigned int)u) << 16);
}
static __device__ __forceinline__ unsigned short f2bf(float f) {
    unsigned int i = __float_as_uint(f);
    unsigned int r = (i + 0x7FFFu + ((i >> 16) & 1u)) >> 16;
    return (unsigned short)r;
}
static __device__ __forceinline__ float sigmoid_f(float x) {
    return 1.0f / (1.0f + __expf(-x));
}
static __device__ __forceinline__ float tanh_f(float x) {
    return 1.0f - 2.0f / (__expf(2.0f * x) + 1.0f);
}

// async global->LDS, 16B per lane; LDS dest = wave-uniform base + lane*16
static __device__ __forceinline__ void gload16(const void* g, void* l) {
    __builtin_amdgcn_global_load_lds((const __attribute__((address_space(1))) void*)g,
                                     (__attribute__((address_space(3))) void*)l, 16, 0, 0);
}

// ---------------------------------------------------------------------------
// fp32 -> bf16 convert
__global__ __launch_bounds__(256) void k_cvt(const float* __restrict__ in,
                                             unsigned short* __restrict__ out, int n4) {
    int i = blockIdx.x * 256 + threadIdx.x;
    if (i >= n4) return;
    float4 v = reinterpret_cast<const float4*>(in)[i];
    uint2 p;
    p.x = (unsigned int)f2bf(v.x) | ((unsigned int)f2bf(v.y) << 16);
    p.y = (unsigned int)f2bf(v.z) | ((unsigned int)f2bf(v.w) << 16);
    reinterpret_cast<uint2*>(out)[i] = p;
}

// ---------------------------------------------------------------------------
// W[K][N] fp32 -> WT[N][K] bf16
__global__ __launch_bounds__(256) void k_transpose(const float* __restrict__ w,
                                                   unsigned short* __restrict__ wT,
                                                   int K, int N) {
    __shared__ float tile[32][33];
    int nblk = N >> 5;
    int bx = blockIdx.x % nblk;
    int by = blockIdx.x / nblk;
    int lx = threadIdx.x & 31;
    int ly = threadIdx.x >> 5;
    int k0 = by * 32, n0 = bx * 32;
#pragma unroll
    for (int i = 0; i < 32; i += 8)
        tile[ly + i][lx] = w[(size_t)(k0 + ly + i) * N + n0 + lx];
    __syncthreads();
#pragma unroll
    for (int i = 0; i < 32; i += 8)
        wT[(size_t)(n0 + ly + i) * K + k0 + lx] = f2bf(tile[lx][ly + i]);
}

// ---------------------------------------------------------------------------
// xg[B*T][G] = bf16( embed[seq] @ x2h_w + x2h_b )
// 128x128 tile, BK=32, 4 waves (2x2), wave = 64x64 = acc[4][4],
// global_load_lds width-16 staging (per-lane gathered source rows for A).
__global__ __launch_bounds__(256) void k_xg(const int* __restrict__ seq,
                                            const unsigned short* __restrict__ emb,  // [V][E]
                                            const unsigned short* __restrict__ wT,   // [G][E]
                                            const float* __restrict__ bias,          // [G]
                                            unsigned short* __restrict__ xg) {       // [B*T][G]
    const int mt = blockIdx.x & 127;  // 128 M-tiles
    const int nt = blockIdx.x >> 7;   // 32 N-tiles
    const int tid = threadIdx.x;
    const int w = tid >> 6, l = tid & 63, g = l >> 4, li = l & 15;
    const int wr = w >> 1, wc = w & 1;

    __shared__ unsigned short As[128 * 32];  // 8 KB
    __shared__ unsigned short Bs[128 * 32];  // 8 KB
    __shared__ int seqv[128];

    if (tid < 128) seqv[tid] = seq[mt * 128 + tid];
    __syncthreads();

    const int r0 = w * 16 + (l >> 2);
    const int kc = (l & 3) * 8;
    const unsigned short* asrc0 = emb + (size_t)seqv[r0] * E_ + kc;
    const unsigned short* asrc1 = emb + (size_t)seqv[r0 + 64] * E_ + kc;
    const unsigned short* bsrc0 = wT + (size_t)(nt * 128 + r0) * E_ + kc;
    const unsigned short* bsrc1 = wT + (size_t)(nt * 128 + r0 + 64) * E_ + kc;
    char* aldsw = (char*)As + w * 1024;
    char* bldsw = (char*)Bs + w * 1024;

    f32x4 acc[4][4] = {};
    for (int k0 = 0; k0 < E_; k0 += 32) {
        gload16(asrc0 + k0, aldsw);
        gload16(asrc1 + k0, aldsw + 4096);
        gload16(bsrc0 + k0, bldsw);
        gload16(bsrc1 + k0, bldsw + 4096);
        __syncthreads();
        short8 af[4], bf[4];
#pragma unroll
        for (int i = 0; i < 4; ++i) {
            af[i] = *(const short8*)(As + (wr * 64 + i * 16 + li) * 32 + g * 8);
            bf[i] = *(const short8*)(Bs + (wc * 64 + i * 16 + li) * 32 + g * 8);
        }
#pragma unroll
        for (int i = 0; i < 4; ++i)
#pragma unroll
            for (int j = 0; j < 4; ++j)
                acc[i][j] = __builtin_amdgcn_mfma_f32_16x16x32_bf16(af[i], bf[j], acc[i][j], 0, 0, 0);
        __syncthreads();
    }

#pragma unroll
    for (int j = 0; j < 4; ++j) {
        const int col = nt * 128 + wc * 64 + j * 16 + li;
        const float bv = bias[col];
#pragma unroll
        for (int i = 0; i < 4; ++i) {
            const int row = mt * 128 + wr * 64 + i * 16 + g * 4;
#pragma unroll
            for (int r = 0; r < 4; ++r)
                xg[(size_t)(row + r) * G_ + col] = f2bf(acc[i][j][r] + bv);
        }
    }
}

// ---------------------------------------------------------------------------
// Persistent LSTM recurrence, cooperative launch (256 WGs = 1/CU).
// Custom device-scope barrier: per-step counters in d_ws (zeroed each launch),
// one atomicAdd per WG + s_sleep(1) load-acquire spin — replaces the ~67us/step
// cg::grid.sync() (ockl deep-sleep backoff) measured in round 2.
__global__ __launch_bounds__(256) void k_rnn(const unsigned short* __restrict__ xg,  // [B][T][G]
                                             const unsigned short* __restrict__ wT,  // [G][H]
                                             const float* __restrict__ bias,         // [G]
                                             const int* __restrict__ seq_len,        // [B]
                                             unsigned short* __restrict__ h0,        // [B][H]
                                             unsigned short* __restrict__ h1,        // [B][H]
                                             float* __restrict__ hs,                 // [B][T][H]
                                             float* __restrict__ cs,                 // [B][T][H]
                                             unsigned int* __restrict__ bar) {       // [T_]
    const int wg = blockIdx.x;
    const int rb = wg & 3, cb = wg >> 2;
    const int tid = threadIdx.x;
    const int w = tid >> 6, l = tid & 63, g = l >> 4, li = l & 15;

    __shared__ unsigned short Bs[64 * 1024];  // 128 KB

    // stage B once: row n -> wT row (n>>4)*1024 + cb*16 + (n&15); XOR-swizzled granules
    for (int gi = 0; gi < 32; ++gi) {
        int gidx = gi * 256 + tid;
        int row = gidx >> 7, gr = gidx & 127;
        int grow = (row >> 4) * 1024 + cb * 16 + (row & 15);
        int4 v = *(const int4*)(wT + (size_t)grow * H_ + gr * 8);
        int dst = row * 128 + (gr ^ (row & 7));
        *(int4*)((char*)Bs + (size_t)dst * 16) = v;
    }

    const int hc = cb * 16 + li;
    float bv[4];
#pragma unroll
    for (int q = 0; q < 4; ++q) bv[q] = bias[q * 1024 + hc];
    const int m0 = rb * 64 + w * 16 + g * 4;
    int sl[4];
#pragma unroll
    for (int r = 0; r < 4; ++r) sl[r] = seq_len[m0 + r];
    float creg[4] = {0.f, 0.f, 0.f, 0.f};
    float hreg[4] = {0.f, 0.f, 0.f, 0.f};

    const int arow_i = rb * 64 + w * 16 + li;
    const int lx7 = li & 7;
    const char* bbase = (const char*)Bs + li * 2048;

    __syncthreads();  // Bs ready (block-local)

    for (int t = 0; t < T_; ++t) {
        const unsigned short* h_in = (t & 1) ? h1 : h0;
        unsigned short* h_out = (t & 1) ? h0 : h1;
        const unsigned short* arow = h_in + (size_t)arow_i * H_ + g * 8;

        // issue h prefetch first (L2-latency chain feeding MFMA)
        short8 pf[8];
#pragma unroll
        for (int p = 0; p < 8; ++p) pf[p] = *(const short8*)(arow + p * 32);

        // prefetch this step's xg scalars (HBM latency, consumed after GEMM)
        float xgl[4][4];
#pragma unroll
        for (int r = 0; r < 4; ++r) {
            const size_t xoff = ((size_t)(m0 + r) * T_ + t) * G_ + hc;
#pragma unroll
            for (int q = 0; q < 4; ++q) xgl[r][q] = bf2f(xg[xoff + q * 1024]);
        }

        f32x4 acc[4] = {};
#pragma unroll
        for (int kk = 0; kk < 32; ++kk) {
            short8 af = pf[kk & 7];
            if (kk < 24) pf[kk & 7] = *(const short8*)(arow + (kk + 8) * 32);
            const int off = ((kk * 4 + g) ^ lx7) << 4;
#pragma unroll
            for (int q = 0; q < 4; ++q) {
                short8 bf = *(const short8*)(bbase + q * 32768 + off);
                acc[q] = __builtin_amdgcn_mfma_f32_16x16x32_bf16(af, bf, acc[q], 0, 0, 0);
            }
        }

        // pointwise + masked update; lane owns rows m0..m0+3 x col hc
#pragma unroll
        for (int r = 0; r < 4; ++r) {
            const int m = m0 + r;
            float ig = sigmoid_f(acc[0][r] + bv[0] + xgl[r][0]);
            float fg = sigmoid_f(acc[1][r] + bv[1] + xgl[r][1]);
            float gg = tanh_f(acc[2][r] + bv[2] + xgl[r][2]);
            float og = sigmoid_f(acc[3][r] + bv[3] + xgl[r][3]);
            float cn = fg * creg[r] + ig * gg;
            float hn = og * tanh_f(cn);
            bool valid = t < sl[r];
            if (valid) { creg[r] = cn; hreg[r] = hn; }
            h_out[(size_t)m * H_ + hc] = f2bf(hreg[r]);
            const size_t ooff = ((size_t)m * T_ + t) * H_ + hc;
            hs[ooff] = valid ? hn : 0.0f;
            cs[ooff] = valid ? cn : 0.0f;
        }

        if (t < T_ - 1) {
            __threadfence();    // publish h_out at agent scope
            __syncthreads();    // all WG threads published
            if (tid == 0) {
                unsigned prev = __hip_atomic_fetch_add(&bar[t], 1u, __ATOMIC_ACQ_REL,
                                                       __HIP_MEMORY_SCOPE_AGENT);
                if (prev != NWG_ - 1u) {
                    unsigned v;
                    do {
                        __builtin_amdgcn_s_sleep(1);
                        v = __hip_atomic_load(&bar[t], __ATOMIC_ACQUIRE,
                                              __HIP_MEMORY_SCOPE_AGENT);
                    } while (v < (unsigned)NWG_);
                }
            }
            __syncthreads();    // WG proceeds after tid0 saw the barrier
        }
    }
}

// ---------------------------------------------------------------------------
// final_hidden[B][H] = tanh(h_last @ aff_w + aff_b)
__global__ __launch_bounds__(256) void k_final(const unsigned short* __restrict__ h,
                                               const unsigned short* __restrict__ wT,
                                               const float* __restrict__ bias,
                                               float* __restrict__ fin) {
    const int rb = blockIdx.x & 3;
    const int nb = blockIdx.x >> 2;
    const int tid = threadIdx.x;
    const int w = tid >> 6;
    const int l = tid & 63;
    const int g = l >> 4, li = l & 15;

    __shared__ unsigned short As[64][40];
    __shared__ unsigned short Bs[64][40];

    const int srow = tid >> 2;
    const int scol = (tid & 3) * 8;
    const unsigned short* aptr = h + (size_t)(rb * 64 + srow) * H_ + scol;
    const unsigned short* bptr = wT + (size_t)(nb * 64 + srow) * H_ + scol;

    f32x4 acc[4] = {};
    int4 ra = *(const int4*)aptr;
    int4 rb2 = *(const int4*)bptr;
    for (int kk = 0; kk < H_; kk += 32) {
        *(int4*)&As[srow][scol] = ra;
        *(int4*)&Bs[srow][scol] = rb2;
        __syncthreads();
        if (kk + 32 < H_) {
            ra = *(const int4*)(aptr + kk + 32);
            rb2 = *(const int4*)(bptr + kk + 32);
        }
        short8 af = *(const short8*)&As[w * 16 + li][g * 8];
#pragma unroll
        for (int q = 0; q < 4; ++q) {
            short8 bf = *(const short8*)&Bs[q * 16 + li][g * 8];
            acc[q] = __builtin_amdgcn_mfma_f32_16x16x32_bf16(af, bf, acc[q], 0, 0, 0);
        }
        __syncthreads();
    }
    const int m0 = rb * 64 + w * 16 + g * 4;
#pragma unroll
    for (int q = 0; q < 4; ++q) {
        int col = nb * 64 + q * 16 + li;
        float bv = bias[col];
#pragma unroll
        for (int r = 0; r < 4; ++r)
            fin[(size_t)(m0 + r) * H_ + col] = tanh_f(acc[q][r] + bv);
    }
}

// ---------------------------------------------------------------------------
__global__ __launch_bounds__(256) void k_mask(const int* __restrict__ seq_len,
                                              float* __restrict__ mask) {
    int i = blockIdx.x * 256 + threadIdx.x;
    int b = i >> 6, t = i & 63;
    mask[i] = (t < seq_len[b]) ? 1.0f : 0.0f;
}

// ---------------------------------------------------------------------------
extern "C" void kernel_launch(void* const* d_in, const int* in_sizes, int n_in,
                              void* d_out, int out_size, void* d_ws, size_t ws_size,
                              hipStream_t stream) {
    const int* seq = (const int*)d_in[0];
    const int* seq_len = (const int*)d_in[1];
    const float* embed = (const float*)d_in[2];
    const float* x2h_w = (const float*)d_in[3];
    const float* x2h_b = (const float*)d_in[4];
    const float* h2h_w = (const float*)d_in[5];
    const float* h2h_b = (const float*)d_in[6];
    const float* aff_w = (const float*)d_in[7];
    const float* aff_b = (const float*)d_in[8];

    float* out = (float*)d_out;
    float* hs = out;
    float* cs = out + (size_t)B_ * T_ * H_;
    float* fin = cs + (size_t)B_ * T_ * H_;
    float* mask = fin + (size_t)B_ * H_;

    char* p = (char*)d_ws;
    unsigned short* emb_b = (unsigned short*)p; p += (size_t)V_ * E_ * 2;
    unsigned short* x2h_t = (unsigned short*)p; p += (size_t)G_ * E_ * 2;
    unsigned short* h2h_t = (unsigned short*)p; p += (size_t)G_ * H_ * 2;
    unsigned short* aff_t = (unsigned short*)p; p += (size_t)H_ * H_ * 2;
    unsigned short* xg    = (unsigned short*)p; p += (size_t)B_ * T_ * G_ * 2;
    unsigned short* hbuf0 = (unsigned short*)p; p += (size_t)B_ * H_ * 2;
    unsigned short* hbuf1 = (unsigned short*)p; p += (size_t)B_ * H_ * 2;
    unsigned int*   bar   = (unsigned int*)p;   p += T_ * sizeof(unsigned int);

    // 1) precompute bf16 operands
    hipLaunchKernelGGL(k_cvt, dim3((V_ * E_ / 4 + 255) / 256), dim3(256), 0, stream,
                       embed, emb_b, V_ * E_ / 4);
    hipLaunchKernelGGL(k_transpose, dim3((E_ / 32) * (G_ / 32)), dim3(256), 0, stream,
                       x2h_w, x2h_t, E_, G_);
    hipLaunchKernelGGL(k_transpose, dim3((H_ / 32) * (G_ / 32)), dim3(256), 0, stream,
                       h2h_w, h2h_t, H_, G_);
    hipLaunchKernelGGL(k_transpose, dim3((H_ / 32) * (H_ / 32)), dim3(256), 0, stream,
                       aff_w, aff_t, H_, H_);

    // 2) xg = embed[seq] @ x2h_w + b
    hipLaunchKernelGGL(k_xg, dim3(128 * 32), dim3(256), 0, stream,
                       seq, emb_b, x2h_t, x2h_b, xg);

    // 3) zero initial h (ping buffer) + barrier counters (every launch:
    //    replays leave them at NWG_)
    hipMemsetAsync(hbuf0, 0, (size_t)B_ * H_ * 2, stream);
    hipMemsetAsync(bar, 0, T_ * sizeof(unsigned int), stream);

    // 4) persistent cooperative recurrence (custom fast barrier per step)
    {
        const unsigned short* xg_p = xg;
        const unsigned short* wT_p = h2h_t;
        const float* b_p = h2h_b;
        const int* sl_p = seq_len;
        unsigned short* h0_p = hbuf0;
        unsigned short* h1_p = hbuf1;
        float* hs_p = hs;
        float* cs_p = cs;
        unsigned int* bar_p = bar;
        void* args[] = {(void*)&xg_p, (void*)&wT_p, (void*)&b_p, (void*)&sl_p,
                        (void*)&h0_p, (void*)&h1_p, (void*)&hs_p, (void*)&cs_p,
                        (void*)&bar_p};
        hipLaunchCooperativeKernel(reinterpret_cast<void*>(k_rnn), dim3(NWG_), dim3(256),
                                   args, 0, stream);
    }

    // 5) final affine (h after t=63 lives in hbuf0) + mask
    hipLaunchKernelGGL(k_final, dim3(64), dim3(256), 0, stream, hbuf0, aff_t, aff_b, fin);
    hipLaunchKernelGGL(k_mask, dim3(B_ * T_ / 256), dim3(256), 0, stream, seq_len, mask);
}

// Round 4
// 962.248 us; speedup vs baseline: 4.6035x; 3.2589x over previous
//
#include <hip/hip_runtime.h>

// Problem constants
#define B_ 256
#define T_ 64
#define V_ 10000
#define E_ 512
#define H_ 1024
#define G_ 4096   // 4*H
#define NWG_ 256

typedef __attribute__((ext_vector_type(8))) short short8;
typedef __attribute__((ext_vector_type(4))) float f32x4;

static __device__ __forceinline__ float bf2f(unsigned short u) {
    return __uint_as_float(((unsigned int)u) << 16);
}
static __device__ __forceinline__ unsigned short f2bf(float f) {
    unsigned int i = __float_as_uint(f);
    unsigned int r = (i + 0x7FFFu + ((i >> 16) & 1u)) >> 16;
    return (unsigned short)r;
}
static __device__ __forceinline__ float sigmoid_f(float x) {
    return 1.0f / (1.0f + __expf(-x));
}
static __device__ __forceinline__ float tanh_f(float x) {
    return 1.0f - 2.0f / (__expf(2.0f * x) + 1.0f);
}

// async global->LDS, 16B per lane
static __device__ __forceinline__ void gload16(const void* g, void* l) {
    __builtin_amdgcn_global_load_lds((const __attribute__((address_space(1))) void*)g,
                                     (__attribute__((address_space(3))) void*)l, 16, 0, 0);
}

// --- agent-coherent primitives (no cache-maintenance instructions) ----------
// 16B load that bypasses L1/L2 (reads at fabric/L3 coherence point)
#define LD16C(dst, ptr) \
    asm volatile("global_load_dwordx4 %0, %1, off sc0 sc1" : "=v"(dst) : "v"(ptr))
// drain all vmem, then block scheduler motion across (rule #18)
#define DRAIN() do { asm volatile("s_waitcnt vmcnt(0)" ::: "memory"); \
                     __builtin_amdgcn_sched_barrier(0); } while (0)
// 2B coherent store (write-through to fabric)
#define STSHORTC(ptr, val) \
    asm volatile("global_store_short %0, %1, off sc0 sc1" :: "v"(ptr), "v"(val) : "memory")

static __device__ __forceinline__ unsigned ld_u32_cohere(const void* p) {
    unsigned r;
    asm volatile("global_load_dword %0, %1, off sc0 sc1\n\ts_waitcnt vmcnt(0)"
                 : "=v"(r) : "v"(p) : "memory");
    return r;
}

// ---------------------------------------------------------------------------
// fp32 -> bf16 convert
__global__ __launch_bounds__(256) void k_cvt(const float* __restrict__ in,
                                             unsigned short* __restrict__ out, int n4) {
    int i = blockIdx.x * 256 + threadIdx.x;
    if (i >= n4) return;
    float4 v = reinterpret_cast<const float4*>(in)[i];
    uint2 p;
    p.x = (unsigned int)f2bf(v.x) | ((unsigned int)f2bf(v.y) << 16);
    p.y = (unsigned int)f2bf(v.z) | ((unsigned int)f2bf(v.w) << 16);
    reinterpret_cast<uint2*>(out)[i] = p;
}

// ---------------------------------------------------------------------------
// W[K][N] fp32 -> WT[N][K] bf16
__global__ __launch_bounds__(256) void k_transpose(const float* __restrict__ w,
                                                   unsigned short* __restrict__ wT,
                                                   int K, int N) {
    __shared__ float tile[32][33];
    int nblk = N >> 5;
    int bx = blockIdx.x % nblk;
    int by = blockIdx.x / nblk;
    int lx = threadIdx.x & 31;
    int ly = threadIdx.x >> 5;
    int k0 = by * 32, n0 = bx * 32;
#pragma unroll
    for (int i = 0; i < 32; i += 8)
        tile[ly + i][lx] = w[(size_t)(k0 + ly + i) * N + n0 + lx];
    __syncthreads();
#pragma unroll
    for (int i = 0; i < 32; i += 8)
        wT[(size_t)(n0 + ly + i) * K + k0 + lx] = f2bf(tile[lx][ly + i]);
}

// ---------------------------------------------------------------------------
// xg[B*T][G] = bf16( embed[seq] @ x2h_w + x2h_b )
__global__ __launch_bounds__(256) void k_xg(const int* __restrict__ seq,
                                            const unsigned short* __restrict__ emb,  // [V][E]
                                            const unsigned short* __restrict__ wT,   // [G][E]
                                            const float* __restrict__ bias,          // [G]
                                            unsigned short* __restrict__ xg) {       // [B*T][G]
    const int mt = blockIdx.x & 127;
    const int nt = blockIdx.x >> 7;
    const int tid = threadIdx.x;
    const int w = tid >> 6, l = tid & 63, g = l >> 4, li = l & 15;
    const int wr = w >> 1, wc = w & 1;

    __shared__ unsigned short As[128 * 32];
    __shared__ unsigned short Bs[128 * 32];
    __shared__ int seqv[128];

    if (tid < 128) seqv[tid] = seq[mt * 128 + tid];
    __syncthreads();

    const int r0 = w * 16 + (l >> 2);
    const int kc = (l & 3) * 8;
    const unsigned short* asrc0 = emb + (size_t)seqv[r0] * E_ + kc;
    const unsigned short* asrc1 = emb + (size_t)seqv[r0 + 64] * E_ + kc;
    const unsigned short* bsrc0 = wT + (size_t)(nt * 128 + r0) * E_ + kc;
    const unsigned short* bsrc1 = wT + (size_t)(nt * 128 + r0 + 64) * E_ + kc;
    char* aldsw = (char*)As + w * 1024;
    char* bldsw = (char*)Bs + w * 1024;

    f32x4 acc[4][4] = {};
    for (int k0 = 0; k0 < E_; k0 += 32) {
        gload16(asrc0 + k0, aldsw);
        gload16(asrc1 + k0, aldsw + 4096);
        gload16(bsrc0 + k0, bldsw);
        gload16(bsrc1 + k0, bldsw + 4096);
        __syncthreads();
        short8 af[4], bf[4];
#pragma unroll
        for (int i = 0; i < 4; ++i) {
            af[i] = *(const short8*)(As + (wr * 64 + i * 16 + li) * 32 + g * 8);
            bf[i] = *(const short8*)(Bs + (wc * 64 + i * 16 + li) * 32 + g * 8);
        }
#pragma unroll
        for (int i = 0; i < 4; ++i)
#pragma unroll
            for (int j = 0; j < 4; ++j)
                acc[i][j] = __builtin_amdgcn_mfma_f32_16x16x32_bf16(af[i], bf[j], acc[i][j], 0, 0, 0);
        __syncthreads();
    }

#pragma unroll
    for (int j = 0; j < 4; ++j) {
        const int col = nt * 128 + wc * 64 + j * 16 + li;
        const float bv = bias[col];
#pragma unroll
        for (int i = 0; i < 4; ++i) {
            const int row = mt * 128 + wr * 64 + i * 16 + g * 4;
#pragma unroll
            for (int r = 0; r < 4; ++r)
                xg[(size_t)(row + r) * G_ + col] = f2bf(acc[i][j][r] + bv);
        }
    }
}

// ---------------------------------------------------------------------------
// Persistent LSTM recurrence, cooperative launch (256 WGs = 1/CU).
// Cross-WG data (h ping-pong) flows ONLY through sc0sc1 coherent accesses;
// barrier is a relaxed fire-and-forget global_atomic_add + sc0sc1 polling.
// Zero buffer_wbl2 / buffer_inv in the steady-state loop.
__global__ __launch_bounds__(256) void k_rnn(const unsigned short* __restrict__ xg,  // [B][T][G]
                                             const unsigned short* __restrict__ wT,  // [G][H]
                                             const float* __restrict__ bias,         // [G]
                                             const int* __restrict__ seq_len,        // [B]
                                             unsigned short* __restrict__ h0,        // [B][H]
                                             unsigned short* __restrict__ h1,        // [B][H]
                                             float* __restrict__ hs,                 // [B][T][H]
                                             float* __restrict__ cs,                 // [B][T][H]
                                             unsigned int* __restrict__ bar) {       // [T_]
    const int wg = blockIdx.x;
    const int rb = wg & 3, cb = wg >> 2;
    const int tid = threadIdx.x;
    const int w = tid >> 6, l = tid & 63, g = l >> 4, li = l & 15;

    __shared__ unsigned short Bs[64 * 1024];  // 128 KB weights, resident all 64 steps

    // stage B once: row n -> wT row (n>>4)*1024 + cb*16 + (n&15); XOR-swizzled granules
    for (int gi = 0; gi < 32; ++gi) {
        int gidx = gi * 256 + tid;
        int row = gidx >> 7, gr = gidx & 127;
        int grow = (row >> 4) * 1024 + cb * 16 + (row & 15);
        int4 v = *(const int4*)(wT + (size_t)grow * H_ + gr * 8);
        int dst = row * 128 + (gr ^ (row & 7));
        *(int4*)((char*)Bs + (size_t)dst * 16) = v;
    }

    const int hc = cb * 16 + li;
    float bv[4];
#pragma unroll
    for (int q = 0; q < 4; ++q) bv[q] = bias[q * 1024 + hc];
    const int m0 = rb * 64 + w * 16 + g * 4;
    int sl[4];
#pragma unroll
    for (int r = 0; r < 4; ++r) sl[r] = seq_len[m0 + r];
    float creg[4] = {0.f, 0.f, 0.f, 0.f};
    float hreg[4] = {0.f, 0.f, 0.f, 0.f};

    const int arow_i = rb * 64 + w * 16 + li;
    const int lx7 = li & 7;
    const char* bbase = (const char*)Bs + li * 2048;

    __syncthreads();  // Bs ready (block-local)

#define LOADS(buf, c) do { _Pragma("unroll") \
    for (int p = 0; p < 8; ++p) LD16C(buf[p], arowc + ((c) + p) * 64); } while (0)

#define MFMAS(buf, c) do { _Pragma("unroll") \
    for (int p = 0; p < 8; ++p) { \
        const int boff = ((((c) + p) * 4 + g) ^ lx7) << 4; \
        _Pragma("unroll") \
        for (int q = 0; q < 4; ++q) { \
            short8 bfv = *(const short8*)(bbase + q * 32768 + boff); \
            acc[q] = __builtin_amdgcn_mfma_f32_16x16x32_bf16(buf[p], bfv, acc[q], 0, 0, 0); \
        } } } while (0)

    for (int t = 0; t < T_; ++t) {
        const unsigned short* h_in = (t & 1) ? h1 : h0;
        unsigned short* h_out = (t & 1) ? h0 : h1;
        const char* arowc = (const char*)(h_in + (size_t)arow_i * H_ + g * 8);

        // issue xg loads first (plain/cached; values consumed after GEMM);
        // memory-clobber barrier pins their issue above the asm loads so the
        // compiler's waitcnt model stays conservative-safe
        unsigned short xgr[4][4];
#pragma unroll
        for (int r = 0; r < 4; ++r) {
            const size_t xoff = ((size_t)(m0 + r) * T_ + t) * G_ + hc;
#pragma unroll
            for (int q = 0; q < 4; ++q) xgr[r][q] = xg[xoff + q * 1024];
        }
        asm volatile("" ::: "memory");

        // A-fragment pipeline: coherent loads, 8-deep double buffer
        f32x4 acc[4] = {};
        short8 A0[8], A1[8];
        LOADS(A0, 0);
        DRAIN();
        LOADS(A1, 8);
        MFMAS(A0, 0);
        DRAIN();
        LOADS(A0, 16);
        MFMAS(A1, 8);
        DRAIN();
        LOADS(A1, 24);
        MFMAS(A0, 16);
        DRAIN();
        MFMAS(A1, 24);

        // pointwise + masked update; lane owns rows m0..m0+3 x col hc
#pragma unroll
        for (int r = 0; r < 4; ++r) {
            const int m = m0 + r;
            float ig = sigmoid_f(acc[0][r] + bv[0] + bf2f(xgr[r][0]));
            float fg = sigmoid_f(acc[1][r] + bv[1] + bf2f(xgr[r][1]));
            float gg = tanh_f(acc[2][r] + bv[2] + bf2f(xgr[r][2]));
            float og = sigmoid_f(acc[3][r] + bv[3] + bf2f(xgr[r][3]));
            float cn = fg * creg[r] + ig * gg;
            float hn = og * tanh_f(cn);
            bool valid = t < sl[r];
            if (valid) { creg[r] = cn; hreg[r] = hn; }
            STSHORTC(h_out + (size_t)m * H_ + hc, f2bf(hreg[r]));
            const size_t ooff = ((size_t)m * T_ + t) * H_ + hc;
            __builtin_nontemporal_store(valid ? hn : 0.0f, &hs[ooff]);
            __builtin_nontemporal_store(valid ? cn : 0.0f, &cs[ooff]);
        }

        if (t < T_ - 1) {
            DRAIN();           // per-wave: sc1 h-stores fabric-visible
            __syncthreads();   // whole WG published
            if (tid == 0) {
                asm volatile("global_atomic_add %0, %1, off"
                             :: "v"(&bar[t]), "v"(1u) : "memory");
                unsigned v;
                do {
                    __builtin_amdgcn_s_sleep(2);
                    v = ld_u32_cohere(&bar[t]);
                } while (v < (unsigned)NWG_);
            }
            __syncthreads();
        }
    }
#undef LOADS
#undef MFMAS
}

// ---------------------------------------------------------------------------
// final_hidden[B][H] = tanh(h_last @ aff_w + aff_b)
__global__ __launch_bounds__(256) void k_final(const unsigned short* __restrict__ h,
                                               const unsigned short* __restrict__ wT,
                                               const float* __restrict__ bias,
                                               float* __restrict__ fin) {
    const int rb = blockIdx.x & 3;
    const int nb = blockIdx.x >> 2;
    const int tid = threadIdx.x;
    const int w = tid >> 6;
    const int l = tid & 63;
    const int g = l >> 4, li = l & 15;

    __shared__ unsigned short As[64][40];
    __shared__ unsigned short Bs[64][40];

    const int srow = tid >> 2;
    const int scol = (tid & 3) * 8;
    const unsigned short* aptr = h + (size_t)(rb * 64 + srow) * H_ + scol;
    const unsigned short* bptr = wT + (size_t)(nb * 64 + srow) * H_ + scol;

    f32x4 acc[4] = {};
    int4 ra = *(const int4*)aptr;
    int4 rb2 = *(const int4*)bptr;
    for (int kk = 0; kk < H_; kk += 32) {
        *(int4*)&As[srow][scol] = ra;
        *(int4*)&Bs[srow][scol] = rb2;
        __syncthreads();
        if (kk + 32 < H_) {
            ra = *(const int4*)(aptr + kk + 32);
            rb2 = *(const int4*)(bptr + kk + 32);
        }
        short8 af = *(const short8*)&As[w * 16 + li][g * 8];
#pragma unroll
        for (int q = 0; q < 4; ++q) {
            short8 bf = *(const short8*)&Bs[q * 16 + li][g * 8];
            acc[q] = __builtin_amdgcn_mfma_f32_16x16x32_bf16(af, bf, acc[q], 0, 0, 0);
        }
        __syncthreads();
    }
    const int m0 = rb * 64 + w * 16 + g * 4;
#pragma unroll
    for (int q = 0; q < 4; ++q) {
        int col = nb * 64 + q * 16 + li;
        float bv = bias[col];
#pragma unroll
        for (int r = 0; r < 4; ++r)
            fin[(size_t)(m0 + r) * H_ + col] = tanh_f(acc[q][r] + bv);
    }
}

// ---------------------------------------------------------------------------
__global__ __launch_bounds__(256) void k_mask(const int* __restrict__ seq_len,
                                              float* __restrict__ mask) {
    int i = blockIdx.x * 256 + threadIdx.x;
    int b = i >> 6, t = i & 63;
    mask[i] = (t < seq_len[b]) ? 1.0f : 0.0f;
}

// ---------------------------------------------------------------------------
extern "C" void kernel_launch(void* const* d_in, const int* in_sizes, int n_in,
                              void* d_out, int out_size, void* d_ws, size_t ws_size,
                              hipStream_t stream) {
    const int* seq = (const int*)d_in[0];
    const int* seq_len = (const int*)d_in[1];
    const float* embed = (const float*)d_in[2];
    const float* x2h_w = (const float*)d_in[3];
    const float* x2h_b = (const float*)d_in[4];
    const float* h2h_w = (const float*)d_in[5];
    const float* h2h_b = (const float*)d_in[6];
    const float* aff_w = (const float*)d_in[7];
    const float* aff_b = (const float*)d_in[8];

    float* out = (float*)d_out;
    float* hs = out;
    float* cs = out + (size_t)B_ * T_ * H_;
    float* fin = cs + (size_t)B_ * T_ * H_;
    float* mask = fin + (size_t)B_ * H_;

    char* p = (char*)d_ws;
    unsigned short* emb_b = (unsigned short*)p; p += (size_t)V_ * E_ * 2;
    unsigned short* x2h_t = (unsigned short*)p; p += (size_t)G_ * E_ * 2;
    unsigned short* h2h_t = (unsigned short*)p; p += (size_t)G_ * H_ * 2;
    unsigned short* aff_t = (unsigned short*)p; p += (size_t)H_ * H_ * 2;
    unsigned short* xg    = (unsigned short*)p; p += (size_t)B_ * T_ * G_ * 2;
    unsigned short* hbuf0 = (unsigned short*)p; p += (size_t)B_ * H_ * 2;
    unsigned short* hbuf1 = (unsigned short*)p; p += (size_t)B_ * H_ * 2;
    unsigned int*   bar   = (unsigned int*)p;   p += T_ * sizeof(unsigned int);

    // 1) precompute bf16 operands
    hipLaunchKernelGGL(k_cvt, dim3((V_ * E_ / 4 + 255) / 256), dim3(256), 0, stream,
                       embed, emb_b, V_ * E_ / 4);
    hipLaunchKernelGGL(k_transpose, dim3((E_ / 32) * (G_ / 32)), dim3(256), 0, stream,
                       x2h_w, x2h_t, E_, G_);
    hipLaunchKernelGGL(k_transpose, dim3((H_ / 32) * (G_ / 32)), dim3(256), 0, stream,
                       h2h_w, h2h_t, H_, G_);
    hipLaunchKernelGGL(k_transpose, dim3((H_ / 32) * (H_ / 32)), dim3(256), 0, stream,
                       aff_w, aff_t, H_, H_);

    // 2) xg = embed[seq] @ x2h_w + b
    hipLaunchKernelGGL(k_xg, dim3(128 * 32), dim3(256), 0, stream,
                       seq, emb_b, x2h_t, x2h_b, xg);

    // 3) zero initial h (ping buffer) + barrier counters (every launch)
    hipMemsetAsync(hbuf0, 0, (size_t)B_ * H_ * 2, stream);
    hipMemsetAsync(bar, 0, T_ * sizeof(unsigned int), stream);

    // 4) persistent cooperative recurrence
    {
        const unsigned short* xg_p = xg;
        const unsigned short* wT_p = h2h_t;
        const float* b_p = h2h_b;
        const int* sl_p = seq_len;
        unsigned short* h0_p = hbuf0;
        unsigned short* h1_p = hbuf1;
        float* hs_p = hs;
        float* cs_p = cs;
        unsigned int* bar_p = bar;
        void* args[] = {(void*)&xg_p, (void*)&wT_p, (void*)&b_p, (void*)&sl_p,
                        (void*)&h0_p, (void*)&h1_p, (void*)&hs_p, (void*)&cs_p,
                        (void*)&bar_p};
        hipLaunchCooperativeKernel(reinterpret_cast<void*>(k_rnn), dim3(NWG_), dim3(256),
                                   args, 0, stream);
    }

    // 5) final affine (h after t=63 lives in hbuf0) + mask
    hipLaunchKernelGGL(k_final, dim3(64), dim3(256), 0, stream, hbuf0, aff_t, aff_b, fin);
    hipLaunchKernelGGL(k_mask, dim3(B_ * T_ / 256), dim3(256), 0, stream, seq_len, mask);
}

// Round 7
// 795.110 us; speedup vs baseline: 5.5712x; 1.2102x over previous
//
#include <hip/hip_runtime.h>

// Problem constants
#define B_ 256
#define T_ 64
#define V_ 10000
#define E_ 512
#define H_ 1024
#define G_ 4096   // 4*H
#define NWG_ 256

typedef __attribute__((ext_vector_type(8))) short short8;
typedef __attribute__((ext_vector_type(4))) float f32x4;

static __device__ __forceinline__ float bf2f(unsigned short u) {
    return __uint_as_float(((unsigned int)u) << 16);
}
static __device__ __forceinline__ unsigned short f2bf(float f) {
    unsigned int i = __float_as_uint(f);
    unsigned int r = (i + 0x7FFFu + ((i >> 16) & 1u)) >> 16;
    return (unsigned short)r;
}
static __device__ __forceinline__ float sigmoid_f(float x) {
    return 1.0f / (1.0f + __expf(-x));
}
static __device__ __forceinline__ float tanh_f(float x) {
    return 1.0f - 2.0f / (__expf(2.0f * x) + 1.0f);
}

// async global->LDS, 16B per lane
static __device__ __forceinline__ void gload16(const void* g, void* l) {
    __builtin_amdgcn_global_load_lds((const __attribute__((address_space(1))) void*)g,
                                     (__attribute__((address_space(3))) void*)l, 16, 0, 0);
}

// --- agent-coherent primitives (all proven in the round-4 PASS) -------------
// 16B load that bypasses L1/L2 (reads at fabric/L3 coherence point)
#define LD16C(dst, ptr) \
    asm volatile("global_load_dwordx4 %0, %1, off sc0 sc1" : "=v"(dst) : "v"(ptr))
// drain all vmem, then block scheduler motion across (rule #18)
#define DRAIN() do { asm volatile("s_waitcnt vmcnt(0)" ::: "memory"); \
                     __builtin_amdgcn_sched_barrier(0); } while (0)
// 2B coherent store (write-through to fabric)
#define STSHORTC(ptr, val) \
    asm volatile("global_store_short %0, %1, off sc0 sc1" :: "v"(ptr), "v"(val) : "memory")
// 4B coherent store (same class as STSHORTC)
#define STDWC(ptr, val) \
    asm volatile("global_store_dword %0, %1, off sc0 sc1" :: "v"(ptr), "v"(val) : "memory")

static __device__ __forceinline__ unsigned ld_u32_cohere(const void* p) {
    unsigned r;
    asm volatile("global_load_dword %0, %1, off sc0 sc1\n\ts_waitcnt vmcnt(0)"
                 : "=v"(r) : "v"(p) : "memory");
    return r;
}

// ---------------------------------------------------------------------------
// fp32 -> bf16 convert
__global__ __launch_bounds__(256) void k_cvt(const float* __restrict__ in,
                                             unsigned short* __restrict__ out, int n4) {
    int i = blockIdx.x * 256 + threadIdx.x;
    if (i >= n4) return;
    float4 v = reinterpret_cast<const float4*>(in)[i];
    uint2 p;
    p.x = (unsigned int)f2bf(v.x) | ((unsigned int)f2bf(v.y) << 16);
    p.y = (unsigned int)f2bf(v.z) | ((unsigned int)f2bf(v.w) << 16);
    reinterpret_cast<uint2*>(out)[i] = p;
}

// ---------------------------------------------------------------------------
// W[K][N] fp32 -> WT[N][K] bf16
__global__ __launch_bounds__(256) void k_transpose(const float* __restrict__ w,
                                                   unsigned short* __restrict__ wT,
                                                   int K, int N) {
    __shared__ float tile[32][33];
    int nblk = N >> 5;
    int bx = blockIdx.x % nblk;
    int by = blockIdx.x / nblk;
    int lx = threadIdx.x & 31;
    int ly = threadIdx.x >> 5;
    int k0 = by * 32, n0 = bx * 32;
#pragma unroll
    for (int i = 0; i < 32; i += 8)
        tile[ly + i][lx] = w[(size_t)(k0 + ly + i) * N + n0 + lx];
    __syncthreads();
#pragma unroll
    for (int i = 0; i < 32; i += 8)
        wT[(size_t)(n0 + ly + i) * K + k0 + lx] = f2bf(tile[lx][ly + i]);
}

// ---------------------------------------------------------------------------
// xg[B*T][G] = bf16( embed[seq] @ x2h_w + x2h_b )
__global__ __launch_bounds__(256) void k_xg(const int* __restrict__ seq,
                                            const unsigned short* __restrict__ emb,  // [V][E]
                                            const unsigned short* __restrict__ wT,   // [G][E]
                                            const float* __restrict__ bias,          // [G]
                                            unsigned short* __restrict__ xg) {       // [B*T][G]
    const int mt = blockIdx.x & 127;
    const int nt = blockIdx.x >> 7;
    const int tid = threadIdx.x;
    const int w = tid >> 6, l = tid & 63, g = l >> 4, li = l & 15;
    const int wr = w >> 1, wc = w & 1;

    __shared__ unsigned short As[128 * 32];
    __shared__ unsigned short Bs[128 * 32];
    __shared__ int seqv[128];

    if (tid < 128) seqv[tid] = seq[mt * 128 + tid];
    __syncthreads();

    const int r0 = w * 16 + (l >> 2);
    const int kc = (l & 3) * 8;
    const unsigned short* asrc0 = emb + (size_t)seqv[r0] * E_ + kc;
    const unsigned short* asrc1 = emb + (size_t)seqv[r0 + 64] * E_ + kc;
    const unsigned short* bsrc0 = wT + (size_t)(nt * 128 + r0) * E_ + kc;
    const unsigned short* bsrc1 = wT + (size_t)(nt * 128 + r0 + 64) * E_ + kc;
    char* aldsw = (char*)As + w * 1024;
    char* bldsw = (char*)Bs + w * 1024;

    f32x4 acc[4][4] = {};
    for (int k0 = 0; k0 < E_; k0 += 32) {
        gload16(asrc0 + k0, aldsw);
        gload16(asrc1 + k0, aldsw + 4096);
        gload16(bsrc0 + k0, bldsw);
        gload16(bsrc1 + k0, bldsw + 4096);
        __syncthreads();
        short8 af[4], bf[4];
#pragma unroll
        for (int i = 0; i < 4; ++i) {
            af[i] = *(const short8*)(As + (wr * 64 + i * 16 + li) * 32 + g * 8);
            bf[i] = *(const short8*)(Bs + (wc * 64 + i * 16 + li) * 32 + g * 8);
        }
#pragma unroll
        for (int i = 0; i < 4; ++i)
#pragma unroll
            for (int j = 0; j < 4; ++j)
                acc[i][j] = __builtin_amdgcn_mfma_f32_16x16x32_bf16(af[i], bf[j], acc[i][j], 0, 0, 0);
        __syncthreads();
    }

#pragma unroll
    for (int j = 0; j < 4; ++j) {
        const int col = nt * 128 + wc * 64 + j * 16 + li;
        const float bv = bias[col];
#pragma unroll
        for (int i = 0; i < 4; ++i) {
            const int row = mt * 128 + wr * 64 + i * 16 + g * 4;
#pragma unroll
            for (int r = 0; r < 4; ++r)
                xg[(size_t)(row + r) * G_ + col] = f2bf(acc[i][j][r] + bv);
        }
    }
}

// ---------------------------------------------------------------------------
// Persistent LSTM recurrence, cooperative launch (256 WGs = 1/CU).
// Body = round-4 k_rnn verbatim (proven PASS). One change: the contended
// global atomic barrier is replaced by a flag barrier scoped to the rb-group,
// with rb = wg>>6 so producers of row-block rb are exactly flags[rb*64..+63].
// Signal: one coherent dword store per WG. Wait: 64 lanes of wave 0 each spin
// on one flag via ld_u32_cohere (divergent exit == all producers done).
__global__ __launch_bounds__(256) void k_rnn(const unsigned short* __restrict__ xg,  // [B][T][G]
                                             const unsigned short* __restrict__ wT,  // [G][H]
                                             const float* __restrict__ bias,         // [G]
                                             const int* __restrict__ seq_len,        // [B]
                                             unsigned short* __restrict__ h0,        // [B][H]
                                             unsigned short* __restrict__ h1,        // [B][H]
                                             float* __restrict__ hs,                 // [B][T][H]
                                             float* __restrict__ cs,                 // [B][T][H]
                                             unsigned int* __restrict__ flags) {     // [NWG_]
    const int wg = blockIdx.x;
    const int rb = wg >> 6, cb = wg & 63;   // rb-group contiguous in wg
    const int tid = threadIdx.x;
    const int w = tid >> 6, l = tid & 63, g = l >> 4, li = l & 15;

    __shared__ unsigned short Bs[64 * 1024];  // 128 KB weights, resident all 64 steps

    // stage B once: row n -> wT row (n>>4)*1024 + cb*16 + (n&15); XOR-swizzled granules
    for (int gi = 0; gi < 32; ++gi) {
        int gidx = gi * 256 + tid;
        int row = gidx >> 7, gr = gidx & 127;
        int grow = (row >> 4) * 1024 + cb * 16 + (row & 15);
        int4 v = *(const int4*)(wT + (size_t)grow * H_ + gr * 8);
        int dst = row * 128 + (gr ^ (row & 7));
        *(int4*)((char*)Bs + (size_t)dst * 16) = v;
    }

    const int hc = cb * 16 + li;
    float bv[4];
#pragma unroll
    for (int q = 0; q < 4; ++q) bv[q] = bias[q * 1024 + hc];
    const int m0 = rb * 64 + w * 16 + g * 4;
    int sl[4];
#pragma unroll
    for (int r = 0; r < 4; ++r) sl[r] = seq_len[m0 + r];
    float creg[4] = {0.f, 0.f, 0.f, 0.f};
    float hreg[4] = {0.f, 0.f, 0.f, 0.f};

    const int arow_i = rb * 64 + w * 16 + li;
    const int lx7 = li & 7;
    const char* bbase = (const char*)Bs + li * 2048;
    // wave-0 poll target: lane tid covers flag rb*64 + tid
    const unsigned int* fp = flags + (rb << 6) + tid;

    __syncthreads();  // Bs ready (block-local)

#define LOADS(buf, c) do { _Pragma("unroll") \
    for (int p = 0; p < 8; ++p) LD16C(buf[p], arowc + ((c) + p) * 64); } while (0)

#define MFMAS(buf, c) do { _Pragma("unroll") \
    for (int p = 0; p < 8; ++p) { \
        const int boff = ((((c) + p) * 4 + g) ^ lx7) << 4; \
        _Pragma("unroll") \
        for (int q = 0; q < 4; ++q) { \
            short8 bfv = *(const short8*)(bbase + q * 32768 + boff); \
            acc[q] = __builtin_amdgcn_mfma_f32_16x16x32_bf16(buf[p], bfv, acc[q], 0, 0, 0); \
        } } } while (0)

    for (int t = 0; t < T_; ++t) {
        const unsigned short* h_in = (t & 1) ? h1 : h0;
        unsigned short* h_out = (t & 1) ? h0 : h1;
        const char* arowc = (const char*)(h_in + (size_t)arow_i * H_ + g * 8);

        // issue xg loads first (plain/cached; values consumed after GEMM);
        // memory-clobber barrier pins their issue above the asm loads so the
        // compiler's waitcnt model stays conservative-safe
        unsigned short xgr[4][4];
#pragma unroll
        for (int r = 0; r < 4; ++r) {
            const size_t xoff = ((size_t)(m0 + r) * T_ + t) * G_ + hc;
#pragma unroll
            for (int q = 0; q < 4; ++q) xgr[r][q] = xg[xoff + q * 1024];
        }
        asm volatile("" ::: "memory");

        // A-fragment pipeline: coherent loads, 8-deep double buffer
        f32x4 acc[4] = {};
        short8 A0[8], A1[8];
        LOADS(A0, 0);
        DRAIN();
        LOADS(A1, 8);
        MFMAS(A0, 0);
        DRAIN();
        LOADS(A0, 16);
        MFMAS(A1, 8);
        DRAIN();
        LOADS(A1, 24);
        MFMAS(A0, 16);
        DRAIN();
        MFMAS(A1, 24);

        // pointwise + masked update; lane owns rows m0..m0+3 x col hc
#pragma unroll
        for (int r = 0; r < 4; ++r) {
            const int m = m0 + r;
            float ig = sigmoid_f(acc[0][r] + bv[0] + bf2f(xgr[r][0]));
            float fg = sigmoid_f(acc[1][r] + bv[1] + bf2f(xgr[r][1]));
            float gg = tanh_f(acc[2][r] + bv[2] + bf2f(xgr[r][2]));
            float og = sigmoid_f(acc[3][r] + bv[3] + bf2f(xgr[r][3]));
            float cn = fg * creg[r] + ig * gg;
            float hn = og * tanh_f(cn);
            bool valid = t < sl[r];
            if (valid) { creg[r] = cn; hreg[r] = hn; }
            STSHORTC(h_out + (size_t)m * H_ + hc, f2bf(hreg[r]));
            const size_t ooff = ((size_t)m * T_ + t) * H_ + hc;
            __builtin_nontemporal_store(valid ? hn : 0.0f, &hs[ooff]);
            __builtin_nontemporal_store(valid ? cn : 0.0f, &cs[ooff]);
        }

        // ---- rb-group flag barrier (contention-free) ----
        if (t < T_ - 1) {
            DRAIN();          // h_out stores fabric-visible (per wave)
            __syncthreads();  // whole WG published
            const unsigned int tp1 = (unsigned int)(t + 1);
            if (tid == 0) {
                STDWC(flags + wg, tp1);
            }
            if (tid < 64) {   // lane i waits for producer WG rb*64+i
                while (ld_u32_cohere(fp) < tp1) __builtin_amdgcn_s_sleep(1);
            }
            __syncthreads();
        }
    }
#undef LOADS
#undef MFMAS
}

// ---------------------------------------------------------------------------
// final_hidden[B][H] = tanh(h_last @ aff_w + aff_b)
__global__ __launch_bounds__(256) void k_final(const unsigned short* __restrict__ h,
                                               const unsigned short* __restrict__ wT,
                                               const float* __restrict__ bias,
                                               float* __restrict__ fin) {
    const int rb = blockIdx.x & 3;
    const int nb = blockIdx.x >> 2;
    const int tid = threadIdx.x;
    const int w = tid >> 6;
    const int l = tid & 63;
    const int g = l >> 4, li = l & 15;

    __shared__ unsigned short As[64][40];
    __shared__ unsigned short Bs[64][40];

    const int srow = tid >> 2;
    const int scol = (tid & 3) * 8;
    const unsigned short* aptr = h + (size_t)(rb * 64 + srow) * H_ + scol;
    const unsigned short* bptr = wT + (size_t)(nb * 64 + srow) * H_ + scol;

    f32x4 acc[4] = {};
    int4 ra = *(const int4*)aptr;
    int4 rb2 = *(const int4*)bptr;
    for (int kk = 0; kk < H_; kk += 32) {
        *(int4*)&As[srow][scol] = ra;
        *(int4*)&Bs[srow][scol] = rb2;
        __syncthreads();
        if (kk + 32 < H_) {
            ra = *(const int4*)(aptr + kk + 32);
            rb2 = *(const int4*)(bptr + kk + 32);
        }
        short8 af = *(const short8*)&As[w * 16 + li][g * 8];
#pragma unroll
        for (int q = 0; q < 4; ++q) {
            short8 bf = *(const short8*)&Bs[q * 16 + li][g * 8];
            acc[q] = __builtin_amdgcn_mfma_f32_16x16x32_bf16(af, bf, acc[q], 0, 0, 0);
        }
        __syncthreads();
    }
    const int m0 = rb * 64 + w * 16 + g * 4;
#pragma unroll
    for (int q = 0; q < 4; ++q) {
        int col = nb * 64 + q * 16 + li;
        float bv = bias[col];
#pragma unroll
        for (int r = 0; r < 4; ++r)
            fin[(size_t)(m0 + r) * H_ + col] = tanh_f(acc[q][r] + bv);
    }
}

// ---------------------------------------------------------------------------
__global__ __launch_bounds__(256) void k_mask(const int* __restrict__ seq_len,
                                              float* __restrict__ mask) {
    int i = blockIdx.x * 256 + threadIdx.x;
    int b = i >> 6, t = i & 63;
    mask[i] = (t < seq_len[b]) ? 1.0f : 0.0f;
}

// ---------------------------------------------------------------------------
extern "C" void kernel_launch(void* const* d_in, const int* in_sizes, int n_in,
                              void* d_out, int out_size, void* d_ws, size_t ws_size,
                              hipStream_t stream) {
    const int* seq = (const int*)d_in[0];
    const int* seq_len = (const int*)d_in[1];
    const float* embed = (const float*)d_in[2];
    const float* x2h_w = (const float*)d_in[3];
    const float* x2h_b = (const float*)d_in[4];
    const float* h2h_w = (const float*)d_in[5];
    const float* h2h_b = (const float*)d_in[6];
    const float* aff_w = (const float*)d_in[7];
    const float* aff_b = (const float*)d_in[8];

    float* out = (float*)d_out;
    float* hs = out;
    float* cs = out + (size_t)B_ * T_ * H_;
    float* fin = cs + (size_t)B_ * T_ * H_;
    float* mask = fin + (size_t)B_ * H_;

    char* p = (char*)d_ws;
    unsigned short* emb_b = (unsigned short*)p; p += (size_t)V_ * E_ * 2;
    unsigned short* x2h_t = (unsigned short*)p; p += (size_t)G_ * E_ * 2;
    unsigned short* h2h_t = (unsigned short*)p; p += (size_t)G_ * H_ * 2;
    unsigned short* aff_t = (unsigned short*)p; p += (size_t)H_ * H_ * 2;
    unsigned short* xg    = (unsigned short*)p; p += (size_t)B_ * T_ * G_ * 2;
    unsigned short* hbuf0 = (unsigned short*)p; p += (size_t)B_ * H_ * 2;
    unsigned short* hbuf1 = (unsigned short*)p; p += (size_t)B_ * H_ * 2;
    unsigned int*   flags = (unsigned int*)p;   p += NWG_ * sizeof(unsigned int);

    // 1) precompute bf16 operands
    hipLaunchKernelGGL(k_cvt, dim3((V_ * E_ / 4 + 255) / 256), dim3(256), 0, stream,
                       embed, emb_b, V_ * E_ / 4);
    hipLaunchKernelGGL(k_transpose, dim3((E_ / 32) * (G_ / 32)), dim3(256), 0, stream,
                       x2h_w, x2h_t, E_, G_);
    hipLaunchKernelGGL(k_transpose, dim3((H_ / 32) * (G_ / 32)), dim3(256), 0, stream,
                       h2h_w, h2h_t, H_, G_);
    hipLaunchKernelGGL(k_transpose, dim3((H_ / 32) * (H_ / 32)), dim3(256), 0, stream,
                       aff_w, aff_t, H_, H_);

    // 2) xg = embed[seq] @ x2h_w + b
    hipLaunchKernelGGL(k_xg, dim3(128 * 32), dim3(256), 0, stream,
                       seq, emb_b, x2h_t, x2h_b, xg);

    // 3) zero initial h (ping buffer) + flags (every launch — replays leave them at T-1)
    hipMemsetAsync(hbuf0, 0, (size_t)B_ * H_ * 2, stream);
    hipMemsetAsync(flags, 0, NWG_ * sizeof(unsigned int), stream);

    // 4) persistent cooperative recurrence
    {
        const unsigned short* xg_p = xg;
        const unsigned short* wT_p = h2h_t;
        const float* b_p = h2h_b;
        const int* sl_p = seq_len;
        unsigned short* h0_p = hbuf0;
        unsigned short* h1_p = hbuf1;
        float* hs_p = hs;
        float* cs_p = cs;
        unsigned int* fl_p = flags;
        void* args[] = {(void*)&xg_p, (void*)&wT_p, (void*)&b_p, (void*)&sl_p,
                        (void*)&h0_p, (void*)&h1_p, (void*)&hs_p, (void*)&cs_p,
                        (void*)&fl_p};
        hipLaunchCooperativeKernel(reinterpret_cast<void*>(k_rnn), dim3(NWG_), dim3(256),
                                   args, 0, stream);
    }

    // 5) final affine (h after t=63 lives in hbuf0) + mask
    hipLaunchKernelGGL(k_final, dim3(64), dim3(256), 0, stream, hbuf0, aff_t, aff_b, fin);
    hipLaunchKernelGGL(k_mask, dim3(B_ * T_ / 256), dim3(256), 0, stream, seq_len, mask);
}

// Round 8
// 674.796 us; speedup vs baseline: 6.5646x; 1.1783x over previous
//
#include <hip/hip_runtime.h>

// Problem constants
#define B_ 256
#define T_ 64
#define V_ 10000
#define E_ 512
#define H_ 1024
#define G_ 4096   // 4*H
#define NWG_ 256

typedef __attribute__((ext_vector_type(8))) short short8;
typedef __attribute__((ext_vector_type(4))) float f32x4;

static __device__ __forceinline__ float bf2f(unsigned short u) {
    return __uint_as_float(((unsigned int)u) << 16);
}
static __device__ __forceinline__ unsigned short f2bf(float f) {
    unsigned int i = __float_as_uint(f);
    unsigned int r = (i + 0x7FFFu + ((i >> 16) & 1u)) >> 16;
    return (unsigned short)r;
}
static __device__ __forceinline__ float sigmoid_f(float x) {
    return 1.0f / (1.0f + __expf(-x));
}
static __device__ __forceinline__ float tanh_f(float x) {
    return 1.0f - 2.0f / (__expf(2.0f * x) + 1.0f);
}

// async global->LDS, 16B per lane
static __device__ __forceinline__ void gload16(const void* g, void* l) {
    __builtin_amdgcn_global_load_lds((const __attribute__((address_space(1))) void*)g,
                                     (__attribute__((address_space(3))) void*)l, 16, 0, 0);
}

// --- agent-coherent primitives (all proven in rounds 4/7 PASS) --------------
// 16B load that bypasses L1/L2 (reads at fabric/L3 coherence point)
#define LD16C(dst, ptr) \
    asm volatile("global_load_dwordx4 %0, %1, off sc0 sc1" : "=v"(dst) : "v"(ptr))
// drain all vmem, then block scheduler motion across (rule #18)
#define DRAIN() do { asm volatile("s_waitcnt vmcnt(0)" ::: "memory"); \
                     __builtin_amdgcn_sched_barrier(0); } while (0)
// 2B coherent store (write-through to fabric)
#define STSHORTC(ptr, val) \
    asm volatile("global_store_short %0, %1, off sc0 sc1" :: "v"(ptr), "v"(val) : "memory")
// 4B coherent store
#define STDWC(ptr, val) \
    asm volatile("global_store_dword %0, %1, off sc0 sc1" :: "v"(ptr), "v"(val) : "memory")

static __device__ __forceinline__ unsigned ld_u32_cohere(const void* p) {
    unsigned r;
    asm volatile("global_load_dword %0, %1, off sc0 sc1\n\ts_waitcnt vmcnt(0)"
                 : "=v"(r) : "v"(p) : "memory");
    return r;
}

// ---------------------------------------------------------------------------
// fp32 -> bf16 convert
__global__ __launch_bounds__(256) void k_cvt(const float* __restrict__ in,
                                             unsigned short* __restrict__ out, int n4) {
    int i = blockIdx.x * 256 + threadIdx.x;
    if (i >= n4) return;
    float4 v = reinterpret_cast<const float4*>(in)[i];
    uint2 p;
    p.x = (unsigned int)f2bf(v.x) | ((unsigned int)f2bf(v.y) << 16);
    p.y = (unsigned int)f2bf(v.z) | ((unsigned int)f2bf(v.w) << 16);
    reinterpret_cast<uint2*>(out)[i] = p;
}

// ---------------------------------------------------------------------------
// W[K][N] fp32 -> WT[N][K] bf16
__global__ __launch_bounds__(256) void k_transpose(const float* __restrict__ w,
                                                   unsigned short* __restrict__ wT,
                                                   int K, int N) {
    __shared__ float tile[32][33];
    int nblk = N >> 5;
    int bx = blockIdx.x % nblk;
    int by = blockIdx.x / nblk;
    int lx = threadIdx.x & 31;
    int ly = threadIdx.x >> 5;
    int k0 = by * 32, n0 = bx * 32;
#pragma unroll
    for (int i = 0; i < 32; i += 8)
        tile[ly + i][lx] = w[(size_t)(k0 + ly + i) * N + n0 + lx];
    __syncthreads();
#pragma unroll
    for (int i = 0; i < 32; i += 8)
        wT[(size_t)(n0 + ly + i) * K + k0 + lx] = f2bf(tile[lx][ly + i]);
}

// ---------------------------------------------------------------------------
// xg[B*T][G] = bf16( embed[seq] @ x2h_w + x2h_b )
__global__ __launch_bounds__(256) void k_xg(const int* __restrict__ seq,
                                            const unsigned short* __restrict__ emb,  // [V][E]
                                            const unsigned short* __restrict__ wT,   // [G][E]
                                            const float* __restrict__ bias,          // [G]
                                            unsigned short* __restrict__ xg) {       // [B*T][G]
    const int mt = blockIdx.x & 127;
    const int nt = blockIdx.x >> 7;
    const int tid = threadIdx.x;
    const int w = tid >> 6, l = tid & 63, g = l >> 4, li = l & 15;
    const int wr = w >> 1, wc = w & 1;

    __shared__ unsigned short As[128 * 32];
    __shared__ unsigned short Bs[128 * 32];
    __shared__ int seqv[128];

    if (tid < 128) seqv[tid] = seq[mt * 128 + tid];
    __syncthreads();

    const int r0 = w * 16 + (l >> 2);
    const int kc = (l & 3) * 8;
    const unsigned short* asrc0 = emb + (size_t)seqv[r0] * E_ + kc;
    const unsigned short* asrc1 = emb + (size_t)seqv[r0 + 64] * E_ + kc;
    const unsigned short* bsrc0 = wT + (size_t)(nt * 128 + r0) * E_ + kc;
    const unsigned short* bsrc1 = wT + (size_t)(nt * 128 + r0 + 64) * E_ + kc;
    char* aldsw = (char*)As + w * 1024;
    char* bldsw = (char*)Bs + w * 1024;

    f32x4 acc[4][4] = {};
    for (int k0 = 0; k0 < E_; k0 += 32) {
        gload16(asrc0 + k0, aldsw);
        gload16(asrc1 + k0, aldsw + 4096);
        gload16(bsrc0 + k0, bldsw);
        gload16(bsrc1 + k0, bldsw + 4096);
        __syncthreads();
        short8 af[4], bf[4];
#pragma unroll
        for (int i = 0; i < 4; ++i) {
            af[i] = *(const short8*)(As + (wr * 64 + i * 16 + li) * 32 + g * 8);
            bf[i] = *(const short8*)(Bs + (wc * 64 + i * 16 + li) * 32 + g * 8);
        }
#pragma unroll
        for (int i = 0; i < 4; ++i)
#pragma unroll
            for (int j = 0; j < 4; ++j)
                acc[i][j] = __builtin_amdgcn_mfma_f32_16x16x32_bf16(af[i], bf[j], acc[i][j], 0, 0, 0);
        __syncthreads();
    }

#pragma unroll
    for (int j = 0; j < 4; ++j) {
        const int col = nt * 128 + wc * 64 + j * 16 + li;
        const float bv = bias[col];
#pragma unroll
        for (int i = 0; i < 4; ++i) {
            const int row = mt * 128 + wr * 64 + i * 16 + g * 4;
#pragma unroll
            for (int r = 0; r < 4; ++r)
                xg[(size_t)(row + r) * G_ + col] = f2bf(acc[i][j][r] + bv);
        }
    }
}

// ---------------------------------------------------------------------------
// Persistent LSTM recurrence, cooperative launch (256 WGs = 1/CU).
// rb = wg>>6 (contiguous row group), cb = wg&63. Changes vs round 7:
//  (1) B stored in LDS in MFMA FRAGMENT ORDER: 16B granule (q,kk,lane) at
//      ((q*32+kk)*64+lane)*16 — every ds_read_b128 is 64 lanes x contiguous
//      16B = 1KB linear, conflict-free by construction (r7 counter showed
//      2048 conflict-cycles/WG-step on the XOR layout).
//  (2) signal flag BEFORE the nontemporal hs/cs stores (their ~900cyc HBM
//      ack was inside the pre-signal DRAIN -> on every consumer's path).
//  (3) xg(t+1) prefetched between signal and poll (HBM latency hidden
//      under the barrier wait).
__global__ __launch_bounds__(256) void k_rnn(const unsigned short* __restrict__ xg,  // [B][T][G]
                                             const unsigned short* __restrict__ wT,  // [G][H]
                                             const float* __restrict__ bias,         // [G]
                                             const int* __restrict__ seq_len,        // [B]
                                             unsigned short* __restrict__ h0,        // [B][H]
                                             unsigned short* __restrict__ h1,        // [B][H]
                                             float* __restrict__ hs,                 // [B][T][H]
                                             float* __restrict__ cs,                 // [B][T][H]
                                             unsigned int* __restrict__ flags) {     // [NWG_]
    const int wg = blockIdx.x;
    const int rb = wg >> 6, cb = wg & 63;   // rb-group contiguous in wg
    const int tid = threadIdx.x;
    const int w = tid >> 6, l = tid & 63, g = l >> 4, li = l & 15;

    __shared__ unsigned short Bs[64 * 1024];  // 128 KB weights, fragment order

    // stage B once in fragment order: granule gidx=(q*32+kk)*64+lane holds
    // wT[(q*1024 + cb*16 + (lane&15))*H + kk*32 + (lane>>4)*8 .. +7]
    for (int gi = 0; gi < 32; ++gi) {
        int gidx = gi * 256 + tid;            // 0..8191
        int ls = gidx & 63;
        int kks = (gidx >> 6) & 31;
        int qs = gidx >> 11;
        int col = qs * 1024 + cb * 16 + (ls & 15);
        int ko = kks * 32 + (ls >> 4) * 8;
        int4 v = *(const int4*)(wT + (size_t)col * H_ + ko);
        *(int4*)((char*)Bs + (size_t)gidx * 16) = v;
    }

    const int hc = cb * 16 + li;
    float bv[4];
#pragma unroll
    for (int q = 0; q < 4; ++q) bv[q] = bias[q * 1024 + hc];
    const int m0 = rb * 64 + w * 16 + g * 4;
    int sl[4];
#pragma unroll
    for (int r = 0; r < 4; ++r) sl[r] = seq_len[m0 + r];
    float creg[4] = {0.f, 0.f, 0.f, 0.f};
    float hreg[4] = {0.f, 0.f, 0.f, 0.f};

    const int arow_i = rb * 64 + w * 16 + li;
    const char* bbase = (const char*)Bs + l * 16;   // full lane id: fragment order
    // wave-0 poll target: lane tid covers flag rb*64 + tid
    const unsigned int* fp = flags + (rb << 6) + tid;

    __syncthreads();  // Bs ready (block-local)

#define LOADS(buf, c) do { _Pragma("unroll") \
    for (int p = 0; p < 8; ++p) LD16C(buf[p], arowc + ((c) + p) * 64); } while (0)

// fragment-order B read: uniform offset (q*32+kk)*1024, lane-linear base
#define MFMAS(buf, c) do { _Pragma("unroll") \
    for (int p = 0; p < 8; ++p) { \
        const int kk = (c) + p; \
        _Pragma("unroll") \
        for (int q = 0; q < 4; ++q) { \
            short8 bfv = *(const short8*)(bbase + ((q * 32 + kk) << 10)); \
            acc[q] = __builtin_amdgcn_mfma_f32_16x16x32_bf16(buf[p], bfv, acc[q], 0, 0, 0); \
        } } } while (0)

    // prologue: prefetch xg for t=0
    unsigned short xgr[4][4];
#pragma unroll
    for (int r = 0; r < 4; ++r) {
        const size_t xoff = ((size_t)(m0 + r) * T_ + 0) * G_ + hc;
#pragma unroll
        for (int q = 0; q < 4; ++q) xgr[r][q] = xg[xoff + q * 1024];
    }
    asm volatile("" ::: "memory");

    for (int t = 0; t < T_; ++t) {
        const unsigned short* h_in = (t & 1) ? h1 : h0;
        unsigned short* h_out = (t & 1) ? h0 : h1;
        const char* arowc = (const char*)(h_in + (size_t)arow_i * H_ + g * 8);

        // A-fragment pipeline: coherent loads, 8-deep double buffer
        f32x4 acc[4] = {};
        short8 A0[8], A1[8];
        LOADS(A0, 0);
        DRAIN();
        LOADS(A1, 8);
        MFMAS(A0, 0);
        DRAIN();
        LOADS(A0, 16);
        MFMAS(A1, 8);
        DRAIN();
        LOADS(A1, 24);
        MFMAS(A0, 16);
        DRAIN();
        MFMAS(A1, 24);

        // pointwise + masked update; lane owns rows m0..m0+3 x col hc
        float hsv[4], csv[4];
#pragma unroll
        for (int r = 0; r < 4; ++r) {
            const int m = m0 + r;
            float ig = sigmoid_f(acc[0][r] + bv[0] + bf2f(xgr[r][0]));
            float fg = sigmoid_f(acc[1][r] + bv[1] + bf2f(xgr[r][1]));
            float gg = tanh_f(acc[2][r] + bv[2] + bf2f(xgr[r][2]));
            float og = sigmoid_f(acc[3][r] + bv[3] + bf2f(xgr[r][3]));
            float cn = fg * creg[r] + ig * gg;
            float hn = og * tanh_f(cn);
            bool valid = t < sl[r];
            if (valid) { creg[r] = cn; hreg[r] = hn; }
            hsv[r] = valid ? hn : 0.0f;
            csv[r] = valid ? cn : 0.0f;
            STSHORTC(h_out + (size_t)m * H_ + hc, f2bf(hreg[r]));
        }

        // publish h_out (only the 4 coherent h-stores are pending here)
        DRAIN();
        __syncthreads();      // whole WG published
        const unsigned int tp1 = (unsigned int)(t + 1);
        if (tid == 0) {
            STDWC(flags + wg, tp1);
        }

        // off-critical-path: hs/cs outputs for this step
#pragma unroll
        for (int r = 0; r < 4; ++r) {
            const size_t ooff = ((size_t)(m0 + r) * T_ + t) * H_ + hc;
            __builtin_nontemporal_store(hsv[r], &hs[ooff]);
            __builtin_nontemporal_store(csv[r], &cs[ooff]);
        }

        if (t < T_ - 1) {
            // prefetch next step's xg under the barrier wait
#pragma unroll
            for (int r = 0; r < 4; ++r) {
                const size_t xoff = ((size_t)(m0 + r) * T_ + (t + 1)) * G_ + hc;
#pragma unroll
                for (int q = 0; q < 4; ++q) xgr[r][q] = xg[xoff + q * 1024];
            }
            asm volatile("" ::: "memory");
            if (tid < 64) {   // lane i waits for producer WG rb*64+i
                while (ld_u32_cohere(fp) < tp1) __builtin_amdgcn_s_sleep(1);
            }
            __syncthreads();
        }
    }
#undef LOADS
#undef MFMAS
}

// ---------------------------------------------------------------------------
// final_hidden[B][H] = tanh(h_last @ aff_w + aff_b)
__global__ __launch_bounds__(256) void k_final(const unsigned short* __restrict__ h,
                                               const unsigned short* __restrict__ wT,
                                               const float* __restrict__ bias,
                                               float* __restrict__ fin) {
    const int rb = blockIdx.x & 3;
    const int nb = blockIdx.x >> 2;
    const int tid = threadIdx.x;
    const int w = tid >> 6;
    const int l = tid & 63;
    const int g = l >> 4, li = l & 15;

    __shared__ unsigned short As[64][40];
    __shared__ unsigned short Bs[64][40];

    const int srow = tid >> 2;
    const int scol = (tid & 3) * 8;
    const unsigned short* aptr = h + (size_t)(rb * 64 + srow) * H_ + scol;
    const unsigned short* bptr = wT + (size_t)(nb * 64 + srow) * H_ + scol;

    f32x4 acc[4] = {};
    int4 ra = *(const int4*)aptr;
    int4 rb2 = *(const int4*)bptr;
    for (int kk = 0; kk < H_; kk += 32) {
        *(int4*)&As[srow][scol] = ra;
        *(int4*)&Bs[srow][scol] = rb2;
        __syncthreads();
        if (kk + 32 < H_) {
            ra = *(const int4*)(aptr + kk + 32);
            rb2 = *(const int4*)(bptr + kk + 32);
        }
        short8 af = *(const short8*)&As[w * 16 + li][g * 8];
#pragma unroll
        for (int q = 0; q < 4; ++q) {
            short8 bf = *(const short8*)&Bs[q * 16 + li][g * 8];
            acc[q] = __builtin_amdgcn_mfma_f32_16x16x32_bf16(af, bf, acc[q], 0, 0, 0);
        }
        __syncthreads();
    }
    const int m0 = rb * 64 + w * 16 + g * 4;
#pragma unroll
    for (int q = 0; q < 4; ++q) {
        int col = nb * 64 + q * 16 + li;
        float bv = bias[col];
#pragma unroll
        for (int r = 0; r < 4; ++r)
            fin[(size_t)(m0 + r) * H_ + col] = tanh_f(acc[q][r] + bv);
    }
}

// ---------------------------------------------------------------------------
__global__ __launch_bounds__(256) void k_mask(const int* __restrict__ seq_len,
                                              float* __restrict__ mask) {
    int i = blockIdx.x * 256 + threadIdx.x;
    int b = i >> 6, t = i & 63;
    mask[i] = (t < seq_len[b]) ? 1.0f : 0.0f;
}

// ---------------------------------------------------------------------------
extern "C" void kernel_launch(void* const* d_in, const int* in_sizes, int n_in,
                              void* d_out, int out_size, void* d_ws, size_t ws_size,
                              hipStream_t stream) {
    const int* seq = (const int*)d_in[0];
    const int* seq_len = (const int*)d_in[1];
    const float* embed = (const float*)d_in[2];
    const float* x2h_w = (const float*)d_in[3];
    const float* x2h_b = (const float*)d_in[4];
    const float* h2h_w = (const float*)d_in[5];
    const float* h2h_b = (const float*)d_in[6];
    const float* aff_w = (const float*)d_in[7];
    const float* aff_b = (const float*)d_in[8];

    float* out = (float*)d_out;
    float* hs = out;
    float* cs = out + (size_t)B_ * T_ * H_;
    float* fin = cs + (size_t)B_ * T_ * H_;
    float* mask = fin + (size_t)B_ * H_;

    char* p = (char*)d_ws;
    unsigned short* emb_b = (unsigned short*)p; p += (size_t)V_ * E_ * 2;
    unsigned short* x2h_t = (unsigned short*)p; p += (size_t)G_ * E_ * 2;
    unsigned short* h2h_t = (unsigned short*)p; p += (size_t)G_ * H_ * 2;
    unsigned short* aff_t = (unsigned short*)p; p += (size_t)H_ * H_ * 2;
    unsigned short* xg    = (unsigned short*)p; p += (size_t)B_ * T_ * G_ * 2;
    unsigned short* hbuf0 = (unsigned short*)p; p += (size_t)B_ * H_ * 2;
    unsigned short* hbuf1 = (unsigned short*)p; p += (size_t)B_ * H_ * 2;
    unsigned int*   flags = (unsigned int*)p;   p += NWG_ * sizeof(unsigned int);

    // 1) precompute bf16 operands
    hipLaunchKernelGGL(k_cvt, dim3((V_ * E_ / 4 + 255) / 256), dim3(256), 0, stream,
                       embed, emb_b, V_ * E_ / 4);
    hipLaunchKernelGGL(k_transpose, dim3((E_ / 32) * (G_ / 32)), dim3(256), 0, stream,
                       x2h_w, x2h_t, E_, G_);
    hipLaunchKernelGGL(k_transpose, dim3((H_ / 32) * (G_ / 32)), dim3(256), 0, stream,
                       h2h_w, h2h_t, H_, G_);
    hipLaunchKernelGGL(k_transpose, dim3((H_ / 32) * (H_ / 32)), dim3(256), 0, stream,
                       aff_w, aff_t, H_, H_);

    // 2) xg = embed[seq] @ x2h_w + b
    hipLaunchKernelGGL(k_xg, dim3(128 * 32), dim3(256), 0, stream,
                       seq, emb_b, x2h_t, x2h_b, xg);

    // 3) zero initial h (ping buffer) + flags (every launch — replays leave them at T-1)
    hipMemsetAsync(hbuf0, 0, (size_t)B_ * H_ * 2, stream);
    hipMemsetAsync(flags, 0, NWG_ * sizeof(unsigned int), stream);

    // 4) persistent cooperative recurrence
    {
        const unsigned short* xg_p = xg;
        const unsigned short* wT_p = h2h_t;
        const float* b_p = h2h_b;
        const int* sl_p = seq_len;
        unsigned short* h0_p = hbuf0;
        unsigned short* h1_p = hbuf1;
        float* hs_p = hs;
        float* cs_p = cs;
        unsigned int* fl_p = flags;
        void* args[] = {(void*)&xg_p, (void*)&wT_p, (void*)&b_p, (void*)&sl_p,
                        (void*)&h0_p, (void*)&h1_p, (void*)&hs_p, (void*)&cs_p,
                        (void*)&fl_p};
        hipLaunchCooperativeKernel(reinterpret_cast<void*>(k_rnn), dim3(NWG_), dim3(256),
                                   args, 0, stream);
    }

    // 5) final affine (h after t=63 lives in hbuf0) + mask
    hipLaunchKernelGGL(k_final, dim3(64), dim3(256), 0, stream, hbuf0, aff_t, aff_b, fin);
    hipLaunchKernelGGL(k_mask, dim3(B_ * T_ / 256), dim3(256), 0, stream, seq_len, mask);
}